// Round 3
// baseline (1488.933 us; speedup 1.0000x reference)
//
#include <hip/hip_runtime.h>
#include <cstdint>
#include <cstddef>

typedef __bf16 bf16;
typedef __bf16 bf16x2 __attribute__((ext_vector_type(2)));
typedef __bf16 bf16x4 __attribute__((ext_vector_type(4)));
typedef __bf16 bf16x8 __attribute__((ext_vector_type(8)));
typedef float f32x4 __attribute__((ext_vector_type(4)));

#define D_MODEL 1024
#define ADA_STRIDE 6144
#define ROWS_TOTAL 32768   // 8 * 4096
#define EPS_RMS 1e-5f

// async global->LDS, 16B per lane; LDS dest must be wave-uniform base + lane*16
__device__ __forceinline__ void gld16(const void* g, void* l) {
  __builtin_amdgcn_global_load_lds((const __attribute__((address_space(1))) void*)g,
                                   (__attribute__((address_space(3))) void*)l, 16, 0, 0);
}

// ---------------------------------------------------------------------------
// Weight convert + transpose: Wt[n*K + k] = (bf16) W[k*N + n]
// ---------------------------------------------------------------------------
__global__ void wconvert_t(const float* __restrict__ W, bf16* __restrict__ Wt,
                           int kbits, int N, int total) {
  int i = blockIdx.x * 256 + threadIdx.x;
  if (i >= total) return;
  int K = 1 << kbits;
  int k = i & (K - 1);
  int n = i >> kbits;
  Wt[i] = (bf16)W[(size_t)k * N + n];
}

// ---------------------------------------------------------------------------
// ada = silu(context) @ W_ada + b_ada   (8 x 6144, K=1024)
// ---------------------------------------------------------------------------
__global__ void ada_gemm(const float* __restrict__ ctx, const float* __restrict__ W,
                         const float* __restrict__ bias, float* __restrict__ ada) {
  __shared__ float sc[D_MODEL];
  int b = blockIdx.y;
  int col = blockIdx.x * 256 + threadIdx.x;
  for (int j = threadIdx.x; j < D_MODEL; j += 256) {
    float x = ctx[b * D_MODEL + j];
    sc[j] = x / (1.f + __expf(-x));
  }
  __syncthreads();
  float acc = bias[col];
#pragma unroll 8
  for (int k = 0; k < D_MODEL; ++k)
    acc += sc[k] * W[(size_t)k * ADA_STRIDE + col];
  ada[b * ADA_STRIDE + col] = acc;
}

// ---------------------------------------------------------------------------
// Fused RMSNorm + adaLN modulation, fp32 in -> bf16 out.
// ---------------------------------------------------------------------------
__global__ void rmsnorm_mod(const float* __restrict__ x, const float* __restrict__ scale,
                            const float* __restrict__ ada, int shOff, int scOff,
                            bf16* __restrict__ out) {
  int row = blockIdx.x;
  int b = row >> 12;
  int t = threadIdx.x;
  const float* xr = x + (size_t)row * D_MODEL;
  float4 v = ((const float4*)xr)[t];
  float ss = v.x * v.x + v.y * v.y + v.z * v.z + v.w * v.w;
#pragma unroll
  for (int m = 32; m >= 1; m >>= 1) ss += __shfl_xor(ss, m, 64);
  __shared__ float ws[4];
  if ((t & 63) == 0) ws[t >> 6] = ss;
  __syncthreads();
  float tot = ws[0] + ws[1] + ws[2] + ws[3];
  float rms = rsqrtf(tot * (1.f / D_MODEL) + EPS_RMS);
  const float* ab = ada + b * ADA_STRIDE;
  int d0 = t * 4;
  float vv[4] = {v.x, v.y, v.z, v.w};
  bf16x4 o4;
#pragma unroll
  for (int j = 0; j < 4; ++j) {
    int d = d0 + j;
    float y = vv[j] * rms * scale[d];
    y = y * (1.f + ab[scOff + d]) + ab[shOff + d];
    o4[j] = (bf16)y;
  }
  *(bf16x4*)(out + (size_t)row * D_MODEL + d0) = o4;
}

// ---------------------------------------------------------------------------
// RoPE in place on qkvQK [32768][2048].
// ---------------------------------------------------------------------------
__global__ void rope_kernel(bf16* __restrict__ qk) {
  int gid = blockIdx.x * 256 + threadIdx.x;   // 32768 * 32
  int t = gid >> 5, i = gid & 31;
  int pos = t & 127;
  float fl = __expf((float)i * -0.14391156831f);   // 10000^(-i/64)
  float al = (float)pos * fl, ah = al * 0.01f;
  float sl, cl, sh, ch;
  __sincosf(al, &sl, &cl);
  __sincosf(ah, &sh, &ch);
  bf16* row = qk + (size_t)t * 2048;
  int d0 = i * 2;
#pragma unroll
  for (int h8 = 0; h8 < 16; ++h8) {
    bf16* hp = row + h8 * 128;
    bf16x2 lo = *(bf16x2*)(hp + d0);
    bf16x2 hi = *(bf16x2*)(hp + 64 + d0);
    bf16x2 olo, ohi;
#pragma unroll
    for (int j = 0; j < 2; ++j) {
      float xl = (float)lo[j], xh = (float)hi[j];
      olo[j] = (bf16)(xl * cl - xh * sl);
      ohi[j] = (bf16)(xh * ch + xl * sh);
    }
    *(bf16x2*)(hp + d0) = olo;
    *(bf16x2*)(hp + 64 + d0) = ohi;
  }
}

// ---------------------------------------------------------------------------
// 256x256-tile MFMA bf16 GEMM, BK=64, 512 threads (8 waves, 2M x 4N).
// PERSISTENT blocks: grid = 256 (1/CU), each block loops over output tiles
// (vb += 256); the last K-tile of tile i stages tile i+1's first K-chunk, so
// the global->LDS pipeline never drains across output tiles.
//
// m201-style phase skeleton, 4 phases per K-tile, 2 barriers per phase:
//   { ds_read frags; stage 2 gld16; [counted VMWAIT]; s_barrier;
//     setprio(1); 16 MFMA; setprio(0); s_barrier }
// Reads issue BEFORE the barrier so their latency drains under barrier skew
// and the other wave's MFMA. Counted vmcnt never 0 in steady state.
//
// Chunk landing guarantees (established at the closing barrier of the phase
// BEFORE the read):  ph0 W0=4 -> B-odd(t) for ph1's read;  ph1 W1=4 ->
// A-odd(t) for ph2's read;  ph2 none;  ph3 W3=4 -> A01/B01(t+1) for next
// ph0's reads. Needed loads are always oldest in the vmem FIFO, so epilogue
// stores only cause bounded over-wait at tile boundaries (correct).
//
// LDS buffer (bf16): A[256][64] at 0, B[256][64] at 16384; full 128B rows.
// Swizzle: logical 16B-group g of row r stored at physical g ^ (r&7)
// (measured 0 conflicts). Applied on pre-swizzled GLOBAL source (gld16 dest
// is linear) and on ds_read addresses.
//
// MFMA operand order SWAPPED (first=B-frag): C lane axis = M row, reg axis =
// 4 consecutive N cols -> vectorized stores.
// EPI: 0 = bf16 (+bias[col]), 1 = gelu -> bf16, 2 = resid + g*(v), 3 = += g*v,
//      4 = bf16 (+bias[row]).
// ---------------------------------------------------------------------------
#define GEMM_LDS 131072

#define VMWAIT(N) asm volatile("s_waitcnt vmcnt(" #N ")" ::: "memory")
#define PH_BAR() __builtin_amdgcn_s_barrier()

#define READ_AE() { _Pragma("unroll") for (int m_ = 0; m_ < 4; ++m_) \
  _Pragma("unroll") for (int s_ = 0; s_ < 2; ++s_) \
    a[m_][s_] = *(const bf16x8*)(lds + cb + aRow + m_ * 2048 + (g0 ^ (s_ * 32))); }
#define READ_AO() { _Pragma("unroll") for (int m_ = 0; m_ < 4; ++m_) \
  _Pragma("unroll") for (int s_ = 0; s_ < 2; ++s_) \
    a[m_][s_] = *(const bf16x8*)(lds + cb + aRow + 1024 + m_ * 2048 + (g0 ^ (s_ * 32))); }
#define READ_BE() { _Pragma("unroll") for (int n_ = 0; n_ < 2; ++n_) \
  _Pragma("unroll") for (int s_ = 0; s_ < 2; ++s_) \
    be[n_][s_] = *(const bf16x8*)(lds + cb + bRow + n_ * 2048 + (g0 ^ (s_ * 32))); }
#define READ_BO() { _Pragma("unroll") for (int n_ = 0; n_ < 2; ++n_) \
  _Pragma("unroll") for (int s_ = 0; s_ < 2; ++s_) \
    bo[n_][s_] = *(const bf16x8*)(lds + cb + bRow + 1024 + n_ * 2048 + (g0 ^ (s_ * 32))); }

#define MMPH(MOFF, BREG, NOFF) { __builtin_amdgcn_s_setprio(1); \
  _Pragma("unroll") for (int m_ = 0; m_ < 4; ++m_) \
  _Pragma("unroll") for (int n_ = 0; n_ < 2; ++n_) \
  _Pragma("unroll") for (int s_ = 0; s_ < 2; ++s_) \
    acc[2 * m_ + (MOFF)][2 * n_ + (NOFF)] = __builtin_amdgcn_mfma_f32_16x16x32_bf16( \
        BREG[n_][s_], a[m_][s_], acc[2 * m_ + (MOFF)][2 * n_ + (NOFF)], 0, 0, 0); \
  __builtin_amdgcn_s_setprio(0); }

#define STG_A01() gld16(gAs + ko2, ldAn); gld16(gAs + ko2 + K8, ldAn + 512)
#define STG_B01() gld16(gBs + ko2, ldBn); gld16(gBs + ko2 + K8, ldBn + 512)
#define STG_B23() gld16(gBs + ko2 + K16, ldBn + 1024); gld16(gBs + ko2 + K24, ldBn + 1536)
#define STG_A23() gld16(gAs + ko2 + K16, ldAn + 1024); gld16(gAs + ko2 + K24, ldAn + 1536)

#define KTILE_BODY(W0, W1, W3, S0, S1, S2, S3) { \
    READ_AE(); READ_BE(); \
    S0; \
    VMWAIT(W0); PH_BAR(); \
    MMPH(0, be, 0); \
    PH_BAR(); \
    READ_BO(); \
    S1; \
    VMWAIT(W1); PH_BAR(); \
    MMPH(0, bo, 1); \
    PH_BAR(); \
    READ_AO(); \
    S2; \
    PH_BAR(); \
    MMPH(1, bo, 1); \
    PH_BAR(); \
    S3; \
    VMWAIT(W3); PH_BAR(); \
    MMPH(1, be, 0); \
    PH_BAR(); \
  }

__device__ __forceinline__ void decode_tile(int vb, int nwg, int MT, int NT,
                                            int& tileM, int& tileN) {
  int wgid = (vb & 7) * (nwg >> 3) + (vb >> 3);
  int width = 8 * NT;
  int gid = wgid / width;
  int first = gid * 8;
  int gsize = (MT - first < 8) ? (MT - first) : 8;
  int inG = wgid % width;
  tileM = (first + inG % gsize) << 8;
  tileN = (inG / gsize) << 8;
}

template <int EPI>
__device__ __forceinline__ void epilogue256(
    f32x4 (&acc)[8][4], int tileM, int tileN, int N, int wm, int wn, int lm, int quad,
    const float* __restrict__ bias, bf16* __restrict__ outB, float* __restrict__ outF,
    const float* __restrict__ resid, const float* __restrict__ ada, int gOff) {
#pragma unroll
  for (int mi = 0; mi < 8; ++mi) {
    int grow = tileM + wm * 128 + mi * 16 + lm;
    int b = grow >> 12;
    float brow = (EPI == 4) ? bias[grow] : 0.f;
#pragma unroll
    for (int ni = 0; ni < 4; ++ni) {
      int col0 = tileN + wn * 64 + ni * 16 + quad * 4;
      size_t idx = (size_t)grow * N + col0;
      if (EPI == 0) {
        float4 b4 = *(const float4*)(bias + col0);
        float bb[4] = {b4.x, b4.y, b4.z, b4.w};
        bf16x4 o;
#pragma unroll
        for (int r = 0; r < 4; ++r) o[r] = (bf16)(acc[mi][ni][r] + bb[r]);
        *(bf16x4*)(outB + idx) = o;
      } else if (EPI == 4) {
        bf16x4 o;
#pragma unroll
        for (int r = 0; r < 4; ++r) o[r] = (bf16)(acc[mi][ni][r] + brow);
        *(bf16x4*)(outB + idx) = o;
      } else if (EPI == 1) {
        float4 b4 = *(const float4*)(bias + col0);
        float bb[4] = {b4.x, b4.y, b4.z, b4.w};
        bf16x4 o;
#pragma unroll
        for (int r = 0; r < 4; ++r) {
          float v = acc[mi][ni][r] + bb[r];
          // exact tanh-gelu via sigmoid: 0.5(1+tanh(s)) = sigmoid(2s)
          float s2 = 1.5957691216057308f * (v + 0.044715f * v * v * v);
          o[r] = (bf16)(v / (1.f + __expf(-s2)));
        }
        *(bf16x4*)(outB + idx) = o;
      } else if (EPI == 2) {
        float4 b4 = *(const float4*)(bias + col0);
        float4 g4 = *(const float4*)(ada + b * ADA_STRIDE + gOff + col0);
        float4 r4 = *(const float4*)(resid + idx);
        float4 o4;
        o4.x = r4.x + g4.x * (acc[mi][ni][0] + b4.x);
        o4.y = r4.y + g4.y * (acc[mi][ni][1] + b4.y);
        o4.z = r4.z + g4.z * (acc[mi][ni][2] + b4.z);
        o4.w = r4.w + g4.w * (acc[mi][ni][3] + b4.w);
        *(float4*)(outF + idx) = o4;
      } else {
        float4 b4 = *(const float4*)(bias + col0);
        float4 g4 = *(const float4*)(ada + b * ADA_STRIDE + gOff + col0);
        float4 r4 = *(const float4*)(outF + idx);
        float4 o4;
        o4.x = r4.x + g4.x * (acc[mi][ni][0] + b4.x);
        o4.y = r4.y + g4.y * (acc[mi][ni][1] + b4.y);
        o4.z = r4.z + g4.z * (acc[mi][ni][2] + b4.z);
        o4.w = r4.w + g4.w * (acc[mi][ni][3] + b4.w);
        *(float4*)(outF + idx) = o4;
      }
    }
  }
}

template <int EPI>
__global__ __launch_bounds__(512, 2) void gemm256(
    const bf16* __restrict__ A, const bf16* __restrict__ Bt,
    const float* __restrict__ bias, int M, int K, int N,
    bf16* __restrict__ outB, float* __restrict__ outF,
    const float* __restrict__ resid, const float* __restrict__ ada, int gOff) {
  extern __shared__ char smem_raw[];
  bf16* lds = (bf16*)smem_raw;   // 2 buffers x 32768 bf16 (A 16K + B 16K each)
  const int tid = threadIdx.x;
  const int lane = tid & 63;
  const int wv = tid >> 6;
  const int wm = wv >> 2;        // 0..1
  const int wn = wv & 3;         // 0..3
  const int lm = lane & 15;
  const int quad = lane >> 4;

  const int MT = M >> 8, NT = N >> 8;
  const int nwg = MT * NT;       // multiple of 256 for all our shapes
  const int nt = K >> 6;

  int vb = blockIdx.x;
  int tileM, tileN;
  decode_tile(vb, nwg, MT, NT, tileM, tileN);

  // ---- staging: wave w covers rows 32w..32w+7 (+8/+16/+24 per load);
  // physical 16B group = lane&7; logical source group pre-swizzled ----
  const int srow = 32 * wv + (lane >> 3);
  const int xg = ((tid & 7) ^ ((tid >> 3) & 7)) * 8;
  const size_t K8 = (size_t)K * 8;
  const size_t K16 = K8 * 2, K24 = K8 * 3;
  const bf16* gA = A + (size_t)(tileM + srow) * K + xg;
  const bf16* gB = Bt + (size_t)(tileN + srow) * K + xg;
  bf16* ldA = lds + wv * 2048 + lane * 8;
  bf16* ldB = ldA + 16384;

  const int g0 = (quad ^ (lm & 7)) * 8;
  const int aRow = wm * 8192 + lm * 64;
  const int bRow = 16384 + wn * 4096 + lm * 64;

  f32x4 acc[8][4];
  bf16x8 a[4][2], be[2][2], bo[2][2];

  // prologue: stage tile-0 K-tile-0 into buffer 0 (order A01,B01,B23,A23)
  {
    const bf16* gAs = gA; const bf16* gBs = gB;
    bf16* ldAn = ldA; bf16* ldBn = ldB;
    const size_t ko2 = 0;
    STG_A01(); STG_B01(); STG_B23(); STG_A23();
  }
  VMWAIT(4);
  PH_BAR();

  int cb = 0;
  for (;;) {
#pragma unroll
    for (int i = 0; i < 8; ++i)
#pragma unroll
      for (int j = 0; j < 4; ++j) acc[i][j] = (f32x4){0.f, 0.f, 0.f, 0.f};

    const int vnext = vb + 256;
    const bool more = vnext < nwg;

    // steady K-tiles (stage K-tile t+1 of this output tile)
    for (int t = 0; t < nt - 1; ++t) {
      const bf16* gAs = gA; const bf16* gBs = gB;
      bf16* ldAn = ldA + (cb ^ 32768);
      bf16* ldBn = ldB + (cb ^ 32768);
      const size_t ko2 = (size_t)(t + 1) * 64;
      KTILE_BODY(4, 4, 4, STG_A01(), STG_B01(), STG_B23(), STG_A23())
      cb ^= 32768;
    }

    if (more) {
      // last K-tile: stage NEXT output tile's K-tile 0 (pipeline stays warm)
      int tileM2, tileN2;
      decode_tile(vnext, nwg, MT, NT, tileM2, tileN2);
      const bf16* gA2 = A + (size_t)(tileM2 + srow) * K + xg;
      const bf16* gB2 = Bt + (size_t)(tileN2 + srow) * K + xg;
      {
        const bf16* gAs = gA2; const bf16* gBs = gB2;
        bf16* ldAn = ldA + (cb ^ 32768);
        bf16* ldBn = ldB + (cb ^ 32768);
        const size_t ko2 = 0;
        KTILE_BODY(4, 4, 4, STG_A01(), STG_B01(), STG_B23(), STG_A23())
      }
      cb ^= 32768;
      epilogue256<EPI>(acc, tileM, tileN, N, wm, wn, lm, quad,
                       bias, outB, outF, resid, ada, gOff);
      vb = vnext; tileM = tileM2; tileN = tileN2; gA = gA2; gB = gB2;
    } else {
      // final K-tile of final output tile: no staging; drain counted waits
      KTILE_BODY(2, 0, 0, , , , )
      cb ^= 32768;
      epilogue256<EPI>(acc, tileM, tileN, N, wm, wn, lm, quad,
                       bias, outB, outF, resid, ada, gOff);
      break;
    }
  }
}

// ---------------------------------------------------------------------------
// MFMA windowed attention (unchanged).
// ---------------------------------------------------------------------------
#define ATTN_LDS 65536

__global__ __launch_bounds__(256, 2) void attn_kernel(
    const bf16* __restrict__ qk, const bf16* __restrict__ vt, bf16* __restrict__ o) {
  extern __shared__ char smem[];
  bf16* qbuf = (bf16*)smem;            // 128x128 swizzled (Q -> P)
  bf16* kbuf = qbuf + 128 * 128;       // 128x128 swizzled (K -> Vt)
  const int tid = threadIdx.x;
  const int lane = tid & 63;
  const int wv = tid >> 6;
  const int lm = lane & 15;
  const int quad = lane >> 4;
  const int w = blockIdx.x >> 3;
  const int h = blockIdx.x & 7;
  const int wbase = w * 128;

#pragma unroll
  for (int it = 0; it < 8; ++it) {
    int c = it * 256 + tid;
    int r = c >> 4, gst = c & 15;
    int goff = (gst ^ (r & 15)) * 8;
    const bf16* rowp = qk + (size_t)(wbase + r) * 2048 + h * 128 + goff;
    gld16(rowp, qbuf + c * 8);
    gld16(rowp + 1024, kbuf + c * 8);
  }
  __syncthreads();

  const int wq0 = wv * 32;
  f32x4 accS[8][2];
#pragma unroll
  for (int mi = 0; mi < 8; ++mi)
#pragma unroll
    for (int ni = 0; ni < 2; ++ni) accS[mi][ni] = (f32x4){0.f, 0.f, 0.f, 0.f};

#pragma unroll
  for (int s = 0; s < 4; ++s) {
    bf16x8 bq[2], ak[8];
#pragma unroll
    for (int ni = 0; ni < 2; ++ni)
      bq[ni] = *(const bf16x8*)(qbuf + (wq0 + ni * 16 + lm) * 128 + ((s * 4 + quad) ^ lm) * 8);
#pragma unroll
    for (int mi = 0; mi < 8; ++mi)
      ak[mi] = *(const bf16x8*)(kbuf + (mi * 16 + lm) * 128 + ((s * 4 + quad) ^ lm) * 8);
#pragma unroll
    for (int mi = 0; mi < 8; ++mi)
#pragma unroll
      for (int ni = 0; ni < 2; ++ni)
        accS[mi][ni] = __builtin_amdgcn_mfma_f32_16x16x32_bf16(ak[mi], bq[ni], accS[mi][ni], 0, 0, 0);
  }

  const float scl = 0.08838834764831845f;  // 1/sqrt(128)
  float mx[2] = {-1e30f, -1e30f}, sm[2] = {0.f, 0.f};
#pragma unroll
  for (int mi = 0; mi < 8; ++mi)
#pragma unroll
    for (int ni = 0; ni < 2; ++ni)
#pragma unroll
      for (int r = 0; r < 4; ++r) {
        accS[mi][ni][r] *= scl;
        mx[ni] = fmaxf(mx[ni], accS[mi][ni][r]);
      }
#pragma unroll
  for (int ni = 0; ni < 2; ++ni) {
    mx[ni] = fmaxf(mx[ni], __shfl_xor(mx[ni], 16, 64));
    mx[ni] = fmaxf(mx[ni], __shfl_xor(mx[ni], 32, 64));
  }
#pragma unroll
  for (int mi = 0; mi < 8; ++mi)
#pragma unroll
    for (int ni = 0; ni < 2; ++ni)
#pragma unroll
      for (int r = 0; r < 4; ++r) {
        accS[mi][ni][r] = __expf(accS[mi][ni][r] - mx[ni]);
        sm[ni] += accS[mi][ni][r];
      }
#pragma unroll
  for (int ni = 0; ni < 2; ++ni) {
    sm[ni] += __shfl_xor(sm[ni], 16, 64);
    sm[ni] += __shfl_xor(sm[ni], 32, 64);
    sm[ni] = 1.f / sm[ni];
  }
  __syncthreads();

#pragma unroll
  for (int mi = 0; mi < 8; ++mi)
#pragma unroll
    for (int ni = 0; ni < 2; ++ni) {
      int q = wq0 + ni * 16 + lm;
      int gst = (mi * 2 + (quad >> 1)) ^ lm;
      bf16x4 pk;
#pragma unroll
      for (int r = 0; r < 4; ++r) pk[r] = (bf16)(accS[mi][ni][r] * sm[ni]);
      *(bf16x4*)(qbuf + q * 128 + gst * 8 + (quad & 1) * 4) = pk;
    }
#pragma unroll
  for (int it = 0; it < 8; ++it) {
    int c = it * 256 + tid;
    int r = c >> 4, gst = c & 15;
    gld16(vt + (size_t)(h * 128 + r) * 32768 + wbase + (gst ^ (r & 15)) * 8, kbuf + c * 8);
  }
  __syncthreads();

  f32x4 accO[2][8];
#pragma unroll
  for (int mi = 0; mi < 2; ++mi)
#pragma unroll
    for (int ni = 0; ni < 8; ++ni) accO[mi][ni] = (f32x4){0.f, 0.f, 0.f, 0.f};
#pragma unroll
  for (int s = 0; s < 4; ++s) {
    bf16x8 ap[2], bv[8];
#pragma unroll
    for (int mi = 0; mi < 2; ++mi)
      ap[mi] = *(const bf16x8*)(qbuf + (wq0 + mi * 16 + lm) * 128 + ((s * 4 + quad) ^ lm) * 8);
#pragma unroll
    for (int ni = 0; ni < 8; ++ni)
      bv[ni] = *(const bf16x8*)(kbuf + (ni * 16 + lm) * 128 + ((s * 4 + quad) ^ lm) * 8);
#pragma unroll
    for (int mi = 0; mi < 2; ++mi)
#pragma unroll
      for (int ni = 0; ni < 8; ++ni)
        accO[mi][ni] = __builtin_amdgcn_mfma_f32_16x16x32_bf16(ap[mi], bv[ni], accO[mi][ni], 0, 0, 0);
  }

#pragma unroll
  for (int mi = 0; mi < 2; ++mi)
#pragma unroll
    for (int ni = 0; ni < 8; ++ni) {
      int d = ni * 16 + lm;
#pragma unroll
      for (int r = 0; r < 4; ++r) {
        int q = wq0 + mi * 16 + quad * 4 + r;
        o[(size_t)(wbase + q) * 1024 + h * 128 + d] = (bf16)accO[mi][ni][r];
      }
    }
}

// ---------------------------------------------------------------------------
extern "C" void kernel_launch(void* const* d_in, const int* in_sizes, int n_in,
                              void* d_out, int out_size, void* d_ws, size_t ws_size,
                              hipStream_t stream) {
  const float* group_x = (const float*)d_in[0];
  const float* context = (const float*)d_in[1];
  const float* W_ada   = (const float*)d_in[2];
  const float* b_ada   = (const float*)d_in[3];
  const float* scale1  = (const float*)d_in[4];
  const float* W_qkv   = (const float*)d_in[5];
  const float* b_qkv   = (const float*)d_in[6];
  const float* W_out   = (const float*)d_in[7];
  const float* b_out   = (const float*)d_in[8];
  const float* scale2  = (const float*)d_in[9];
  const float* W_ff1   = (const float*)d_in[10];
  const float* b_ff1   = (const float*)d_in[11];
  const float* W_ff2   = (const float*)d_in[12];
  const float* b_ff2   = (const float*)d_in[13];
  float* out = (float*)d_out;

  char* ws = (char*)d_ws;
  float* ada   = (float*)ws;                          // 196,608 B
  bf16* wqkv_t = (bf16*)(ws + 196608);                // 3072x1024 (rows 2048.. are Wv^T)
  bf16* wout_t = wqkv_t + (size_t)3072 * 1024;        // 1024x1024
  bf16* wff1_t = wout_t + (size_t)1024 * 1024;        // 4096x1024
  bf16* wff2_t = wff1_t + (size_t)4096 * 1024;        // 1024x4096
  bf16* bufX   = wff2_t + (size_t)1024 * 4096;        // 32768x1024 (xmod -> o -> hmod)
  bf16* qkvQK  = bufX + (size_t)ROWS_TOTAL * 1024;    // 32768x2048 (roped in place)
  bf16* vtbuf  = qkvQK + (size_t)ROWS_TOTAL * 2048;   // 1024x32768
  bf16* h1     = qkvQK;                               // 32768x4096 aliases qkvQK+vtbuf

  // 0) weight convert+transpose
  wconvert_t<<<dim3(3072 * 1024 / 256), 256, 0, stream>>>(W_qkv, wqkv_t, 10, 3072, 3072 * 1024);
  wconvert_t<<<dim3(1024 * 1024 / 256), 256, 0, stream>>>(W_out, wout_t, 10, 1024, 1024 * 1024);
  wconvert_t<<<dim3(4096 * 1024 / 256), 256, 0, stream>>>(W_ff1, wff1_t, 10, 4096, 4096 * 1024);
  wconvert_t<<<dim3(1024 * 4096 / 256), 256, 0, stream>>>(W_ff2, wff2_t, 12, 1024, 1024 * 4096);

  // 1) ada
  ada_gemm<<<dim3(ADA_STRIDE / 256, 8), 256, 0, stream>>>(context, W_ada, b_ada, ada);

  // 2) xmod
  rmsnorm_mod<<<ROWS_TOTAL, 256, 0, stream>>>(group_x, scale1, ada, 0, 1024, bufX);

  // dynamic-LDS caps for the 256^2 GEMM instantiations
  hipFuncSetAttribute(reinterpret_cast<const void*>(&gemm256<0>),
                      hipFuncAttributeMaxDynamicSharedMemorySize, GEMM_LDS);
  hipFuncSetAttribute(reinterpret_cast<const void*>(&gemm256<1>),
                      hipFuncAttributeMaxDynamicSharedMemorySize, GEMM_LDS);
  hipFuncSetAttribute(reinterpret_cast<const void*>(&gemm256<2>),
                      hipFuncAttributeMaxDynamicSharedMemorySize, GEMM_LDS);
  hipFuncSetAttribute(reinterpret_cast<const void*>(&gemm256<3>),
                      hipFuncAttributeMaxDynamicSharedMemorySize, GEMM_LDS);
  hipFuncSetAttribute(reinterpret_cast<const void*>(&gemm256<4>),
                      hipFuncAttributeMaxDynamicSharedMemorySize, GEMM_LDS);

  // 3a) qk = xmod @ W_qk + b   (M=32768, N=2048, K=1024) — persistent, 4 tiles/block
  gemm256<0><<<dim3(256), 512, GEMM_LDS, stream>>>(
      bufX, wqkv_t, b_qkv, ROWS_TOTAL, 1024, 2048, qkvQK, nullptr, nullptr, nullptr, 0);

  // 3b) vT[vfeat][token] = Wv^T @ xmod^T + b_v[row]  (M=1024, N=32768) — 2 tiles/block
  gemm256<4><<<dim3(256), 512, GEMM_LDS, stream>>>(
      wqkv_t + (size_t)2048 * 1024, bufX, b_qkv + 2048, 1024, 1024, ROWS_TOTAL,
      vtbuf, nullptr, nullptr, nullptr, 0);

  // 3c) rope q,k in place
  rope_kernel<<<dim3(ROWS_TOTAL * 32 / 256), 256, 0, stream>>>(qkvQK);

  // 4) attention -> o (bf16, reuses bufX)
  hipFuncSetAttribute(reinterpret_cast<const void*>(&attn_kernel),
                      hipFuncAttributeMaxDynamicSharedMemorySize, ATTN_LDS);
  attn_kernel<<<dim3(256 * 8), 256, ATTN_LDS, stream>>>(qkvQK, vtbuf, bufX);

  // 5) res2 = group_x + g_msa * (o @ W_out + b_out)  -> d_out (fp32) — 2 tiles/block
  gemm256<2><<<dim3(256), 512, GEMM_LDS, stream>>>(
      bufX, wout_t, b_out, ROWS_TOTAL, 1024, 1024, nullptr, out, group_x, ada, 2048);

  // 6) hmod
  rmsnorm_mod<<<ROWS_TOTAL, 256, 0, stream>>>(out, scale2, ada, 3072, 4096, bufX);

  // 7) h1 = gelu(hmod @ W_ff1 + b_ff1)  (M=32768, N=4096, K=1024) — 8 tiles/block
  gemm256<1><<<dim3(256), 512, GEMM_LDS, stream>>>(
      bufX, wff1_t, b_ff1, ROWS_TOTAL, 1024, 4096, h1, nullptr, nullptr, nullptr, 0);

  // 8) d_out = res2 + g_mlp * (h1 @ W_ff2 + b_ff2)  (K=4096) — 2 tiles/block
  gemm256<3><<<dim3(256), 512, GEMM_LDS, stream>>>(
      h1, wff2_t, b_ff2, ROWS_TOTAL, 4096, 1024, nullptr, out, nullptr, ada, 5120);
}

// Round 4
// 1422.917 us; speedup vs baseline: 1.0464x; 1.0464x over previous
//
#include <hip/hip_runtime.h>
#include <cstdint>
#include <cstddef>

typedef __bf16 bf16;
typedef __bf16 bf16x2 __attribute__((ext_vector_type(2)));
typedef __bf16 bf16x4 __attribute__((ext_vector_type(4)));
typedef __bf16 bf16x8 __attribute__((ext_vector_type(8)));
typedef float f32x4 __attribute__((ext_vector_type(4)));

#define D_MODEL 1024
#define ADA_STRIDE 6144
#define ROWS_TOTAL 32768   // 8 * 4096
#define EPS_RMS 1e-5f

// async global->LDS, 16B per lane; LDS dest must be wave-uniform base + lane*16
__device__ __forceinline__ void gld16(const void* g, void* l) {
  __builtin_amdgcn_global_load_lds((const __attribute__((address_space(1))) void*)g,
                                   (__attribute__((address_space(3))) void*)l, 16, 0, 0);
}

// ---------------------------------------------------------------------------
// Weight convert + transpose: Wt[n*K + k] = (bf16) W[k*N + n]
// ---------------------------------------------------------------------------
__global__ void wconvert_t(const float* __restrict__ W, bf16* __restrict__ Wt,
                           int kbits, int N, int total) {
  int i = blockIdx.x * 256 + threadIdx.x;
  if (i >= total) return;
  int K = 1 << kbits;
  int k = i & (K - 1);
  int n = i >> kbits;
  Wt[i] = (bf16)W[(size_t)k * N + n];
}

// ---------------------------------------------------------------------------
// ada = silu(context) @ W_ada + b_ada   (8 x 6144, K=1024)
// ---------------------------------------------------------------------------
__global__ void ada_gemm(const float* __restrict__ ctx, const float* __restrict__ W,
                         const float* __restrict__ bias, float* __restrict__ ada) {
  __shared__ float sc[D_MODEL];
  int b = blockIdx.y;
  int col = blockIdx.x * 256 + threadIdx.x;
  for (int j = threadIdx.x; j < D_MODEL; j += 256) {
    float x = ctx[b * D_MODEL + j];
    sc[j] = x / (1.f + __expf(-x));
  }
  __syncthreads();
  float acc = bias[col];
#pragma unroll 8
  for (int k = 0; k < D_MODEL; ++k)
    acc += sc[k] * W[(size_t)k * ADA_STRIDE + col];
  ada[b * ADA_STRIDE + col] = acc;
}

// ---------------------------------------------------------------------------
// Fused RMSNorm + adaLN modulation, fp32 in -> bf16 out.
// ---------------------------------------------------------------------------
__global__ void rmsnorm_mod(const float* __restrict__ x, const float* __restrict__ scale,
                            const float* __restrict__ ada, int shOff, int scOff,
                            bf16* __restrict__ out) {
  int row = blockIdx.x;
  int b = row >> 12;
  int t = threadIdx.x;
  const float* xr = x + (size_t)row * D_MODEL;
  float4 v = ((const float4*)xr)[t];
  float ss = v.x * v.x + v.y * v.y + v.z * v.z + v.w * v.w;
#pragma unroll
  for (int m = 32; m >= 1; m >>= 1) ss += __shfl_xor(ss, m, 64);
  __shared__ float ws[4];
  if ((t & 63) == 0) ws[t >> 6] = ss;
  __syncthreads();
  float tot = ws[0] + ws[1] + ws[2] + ws[3];
  float rms = rsqrtf(tot * (1.f / D_MODEL) + EPS_RMS);
  const float* ab = ada + b * ADA_STRIDE;
  int d0 = t * 4;
  float vv[4] = {v.x, v.y, v.z, v.w};
  bf16x4 o4;
#pragma unroll
  for (int j = 0; j < 4; ++j) {
    int d = d0 + j;
    float y = vv[j] * rms * scale[d];
    y = y * (1.f + ab[scOff + d]) + ab[shOff + d];
    o4[j] = (bf16)y;
  }
  *(bf16x4*)(out + (size_t)row * D_MODEL + d0) = o4;
}

// ---------------------------------------------------------------------------
// RoPE in place on qkvQK [32768][2048].
// ---------------------------------------------------------------------------
__global__ void rope_kernel(bf16* __restrict__ qk) {
  int gid = blockIdx.x * 256 + threadIdx.x;   // 32768 * 32
  int t = gid >> 5, i = gid & 31;
  int pos = t & 127;
  float fl = __expf((float)i * -0.14391156831f);   // 10000^(-i/64)
  float al = (float)pos * fl, ah = al * 0.01f;
  float sl, cl, sh, ch;
  __sincosf(al, &sl, &cl);
  __sincosf(ah, &sh, &ch);
  bf16* row = qk + (size_t)t * 2048;
  int d0 = i * 2;
#pragma unroll
  for (int h8 = 0; h8 < 16; ++h8) {
    bf16* hp = row + h8 * 128;
    bf16x2 lo = *(bf16x2*)(hp + d0);
    bf16x2 hi = *(bf16x2*)(hp + 64 + d0);
    bf16x2 olo, ohi;
#pragma unroll
    for (int j = 0; j < 2; ++j) {
      float xl = (float)lo[j], xh = (float)hi[j];
      olo[j] = (bf16)(xl * cl - xh * sl);
      ohi[j] = (bf16)(xh * ch + xl * sh);
    }
    *(bf16x2*)(hp + d0) = olo;
    *(bf16x2*)(hp + 64 + d0) = ohi;
  }
}

// ---------------------------------------------------------------------------
// 256x256-tile MFMA bf16 GEMM, BK=64, 512 threads (8 waves, 2M x 4N),
// 2x64KB LDS double buffer, HALF-TILE (E/O) staging with counted vmcnt(4)
// that NEVER drains in the main loop.
//
// Per K-tile t (slot c = t&1), 2 barriers:
//   VMWAIT(4); BAR            // S_E(t) landed (S_O(t) = the 4 outstanding)
//   read AE,BE (12 ds_read)   // slot c
//   stage S_E(t+1) (4 gld16)  // slot c^1
//   C0 = 16 MFMA (ae x be)    // E-reads drain UNDER C0
//   VMWAIT(4); BAR            // S_O(t) landed (S_E(t+1) = the 4 outstanding)
//   read BO,AO (12 ds_read)
//   stage S_O(t+1) (4 gld16)
//   C1,C2,C3 = 48 MFMA        // O-reads drain UNDER C1
// Register sets ae/ao/be/bo are disjoint per half -> no WAR serialization;
// cluster order (ae·be)(ae·bo)(ao·bo)(ao·be) frees each set before its refill.
//
// E/O row halves ((row&31)<16 vs >=16) align exactly with the frag row sets,
// so chunk staging == consumption granularity. Safety: writes to slot c^1 are
// issued only after the top/mid barriers, which all waves reach only after
// draining their tile-(t-1) reads of slot c^1 (lgkm before their MFMAs).
//
// LDS layout (bf16): A[256][64] at 0, B[256][64] at 16384; full 128B rows.
// Swizzle: logical 16B-group g of row r at physical g ^ (r&7) (measured 0
// conflicts). Applied on pre-swizzled GLOBAL source (gld16 dest is linear)
// and on ds_read addresses.
//
// MFMA operand order SWAPPED (first=B-frag): C lane axis = M row, reg axis =
// 4 consecutive N cols -> vectorized stores.
// EPI: 0 = bf16 (+bias[col]), 1 = gelu -> bf16, 2 = resid + g*(v), 3 = += g*v,
//      4 = bf16 (+bias[row]).
// ---------------------------------------------------------------------------
#define GEMM_LDS 131072

#define VMWAIT(N) asm volatile("s_waitcnt vmcnt(" #N ")" ::: "memory")
#define PH_BAR() __builtin_amdgcn_s_barrier()

#define READ_AE() { _Pragma("unroll") for (int m_ = 0; m_ < 4; ++m_) \
  _Pragma("unroll") for (int s_ = 0; s_ < 2; ++s_) \
    ae[m_][s_] = *(const bf16x8*)(lds + cb + aRow + m_ * 2048 + (g0 ^ (s_ * 32))); }
#define READ_AO() { _Pragma("unroll") for (int m_ = 0; m_ < 4; ++m_) \
  _Pragma("unroll") for (int s_ = 0; s_ < 2; ++s_) \
    ao[m_][s_] = *(const bf16x8*)(lds + cb + aRow + 1024 + m_ * 2048 + (g0 ^ (s_ * 32))); }
#define READ_BE() { _Pragma("unroll") for (int n_ = 0; n_ < 2; ++n_) \
  _Pragma("unroll") for (int s_ = 0; s_ < 2; ++s_) \
    be[n_][s_] = *(const bf16x8*)(lds + cb + bRow + n_ * 2048 + (g0 ^ (s_ * 32))); }
#define READ_BO() { _Pragma("unroll") for (int n_ = 0; n_ < 2; ++n_) \
  _Pragma("unroll") for (int s_ = 0; s_ < 2; ++s_) \
    bo[n_][s_] = *(const bf16x8*)(lds + cb + bRow + 1024 + n_ * 2048 + (g0 ^ (s_ * 32))); }

#define MMPH(AREG, MOFF, BREG, NOFF) { __builtin_amdgcn_s_setprio(1); \
  _Pragma("unroll") for (int m_ = 0; m_ < 4; ++m_) \
  _Pragma("unroll") for (int n_ = 0; n_ < 2; ++n_) \
  _Pragma("unroll") for (int s_ = 0; s_ < 2; ++s_) \
    acc[2 * m_ + (MOFF)][2 * n_ + (NOFF)] = __builtin_amdgcn_mfma_f32_16x16x32_bf16( \
        BREG[n_][s_], AREG[m_][s_], acc[2 * m_ + (MOFF)][2 * n_ + (NOFF)], 0, 0, 0); \
  __builtin_amdgcn_s_setprio(0); }

// E-half: A rows (r&31)<16 and B rows (r&31)<16 (chunks A01, B01)
#define STAGE_E() { gld16(gA + ko2, ldAn); gld16(gA + ko2 + K8, ldAn + 512); \
                    gld16(gB + ko2, ldBn); gld16(gB + ko2 + K8, ldBn + 512); }
// O-half: rows (r&31)>=16 (chunks B23, A23)
#define STAGE_O() { gld16(gB + ko2 + K16, ldBn + 1024); gld16(gB + ko2 + K24, ldBn + 1536); \
                    gld16(gA + ko2 + K16, ldAn + 1024); gld16(gA + ko2 + K24, ldAn + 1536); }

template <int EPI>
__global__ __launch_bounds__(512, 2) void gemm256(
    const bf16* __restrict__ A, const bf16* __restrict__ Bt,
    const float* __restrict__ bias, int M, int K, int N,
    bf16* __restrict__ outB, float* __restrict__ outF,
    const float* __restrict__ resid, const float* __restrict__ ada, int gOff) {
  extern __shared__ char smem_raw[];
  bf16* lds = (bf16*)smem_raw;   // 2 buffers x 32768 bf16 (A 16K + B 16K each)
  const int tid = threadIdx.x;
  const int lane = tid & 63;
  const int wv = tid >> 6;
  const int wm = wv >> 2;        // 0..1
  const int wn = wv & 3;         // 0..3
  const int lm = lane & 15;
  const int quad = lane >> 4;

  // ---- block swizzle: bijective XCD-contiguous remap, then grouped-M ----
  const int MT = M >> 8, NT = N >> 8;
  const int nwg = MT * NT;                 // always a multiple of 8 here
  const int bid = blockIdx.x;
  const int wgid = (bid & 7) * (nwg >> 3) + (bid >> 3);
  const int width = 8 * NT;
  const int gid = wgid / width;
  const int first = gid * 8;
  const int gsize = (MT - first < 8) ? (MT - first) : 8;
  const int inG = wgid % width;
  const int tileM = (first + inG % gsize) << 8;
  const int tileN = (inG / gsize) << 8;

  // ---- staging: wave w covers rows 32w..32w+7 (+8/+16/+24 per load);
  // physical 16B group = lane&7; logical source group pre-swizzled ----
  const int srow = 32 * wv + (lane >> 3);
  const int xg = ((tid & 7) ^ ((tid >> 3) & 7)) * 8;
  const size_t K8 = (size_t)K * 8;
  const size_t K16 = K8 * 2, K24 = K8 * 3;
  const bf16* gA = A + (size_t)(tileM + srow) * K + xg;
  const bf16* gB = Bt + (size_t)(tileN + srow) * K + xg;
  bf16* ldA = lds + wv * 2048 + lane * 8;
  bf16* ldB = ldA + 16384;

  const int g0 = (quad ^ (lm & 7)) * 8;
  const int aRow = wm * 8192 + lm * 64;
  const int bRow = 16384 + wn * 4096 + lm * 64;

  f32x4 acc[8][4];
#pragma unroll
  for (int i = 0; i < 8; ++i)
#pragma unroll
    for (int j = 0; j < 4; ++j) acc[i][j] = (f32x4){0.f, 0.f, 0.f, 0.f};

  bf16x8 ae[4][2], ao[4][2], be[2][2], bo[2][2];

  // prologue: stage K-tile 0 into buffer 0 (E half then O half)
  {
    bf16* ldAn = ldA; bf16* ldBn = ldB;
    const size_t ko2 = 0;
    STAGE_E();
    STAGE_O();
  }

  const int nt = K >> 6;
  int cb = 0;
  // steady K-tiles: stage K-tile t+1
  for (int t = 0; t < nt - 1; ++t) {
    bf16* ldAn = ldA + (cb ^ 32768);
    bf16* ldBn = ldB + (cb ^ 32768);
    const size_t ko2 = (size_t)(t + 1) * 64;
    VMWAIT(4); PH_BAR();                 // S_E(t) landed; S_O(t) in flight
    READ_AE(); READ_BE();
    STAGE_E();
    MMPH(ae, 0, be, 0);                  // C0 — E-reads drain under it
    VMWAIT(4); PH_BAR();                 // S_O(t) landed; S_E(t+1) in flight
    READ_BO(); READ_AO();
    STAGE_O();
    MMPH(ae, 0, bo, 1);                  // C1 — O-reads drain under it
    MMPH(ao, 1, bo, 1);                  // C2
    MMPH(ao, 1, be, 0);                  // C3
    cb ^= 32768;
  }
  // final K-tile: no staging
  {
    VMWAIT(4); PH_BAR();
    READ_AE(); READ_BE();
    MMPH(ae, 0, be, 0);
    VMWAIT(0); PH_BAR();                 // queue empty anyway
    READ_BO(); READ_AO();
    MMPH(ae, 0, bo, 1);
    MMPH(ao, 1, bo, 1);
    MMPH(ao, 1, be, 0);
  }

  // epilogue: lane axis = M row, reg axis = 4 consecutive N cols
#pragma unroll
  for (int mi = 0; mi < 8; ++mi) {
    int grow = tileM + wm * 128 + mi * 16 + lm;
    int b = grow >> 12;
    float brow = (EPI == 4) ? bias[grow] : 0.f;
#pragma unroll
    for (int ni = 0; ni < 4; ++ni) {
      int col0 = tileN + wn * 64 + ni * 16 + quad * 4;
      size_t idx = (size_t)grow * N + col0;
      if (EPI == 0) {
        float4 b4 = *(const float4*)(bias + col0);
        float bb[4] = {b4.x, b4.y, b4.z, b4.w};
        bf16x4 o;
#pragma unroll
        for (int r = 0; r < 4; ++r) o[r] = (bf16)(acc[mi][ni][r] + bb[r]);
        *(bf16x4*)(outB + idx) = o;
      } else if (EPI == 4) {
        bf16x4 o;
#pragma unroll
        for (int r = 0; r < 4; ++r) o[r] = (bf16)(acc[mi][ni][r] + brow);
        *(bf16x4*)(outB + idx) = o;
      } else if (EPI == 1) {
        float4 b4 = *(const float4*)(bias + col0);
        float bb[4] = {b4.x, b4.y, b4.z, b4.w};
        bf16x4 o;
#pragma unroll
        for (int r = 0; r < 4; ++r) {
          float v = acc[mi][ni][r] + bb[r];
          // exact tanh-gelu via sigmoid: 0.5(1+tanh(s)) = sigmoid(2s)
          float s2 = 1.5957691216057308f * (v + 0.044715f * v * v * v);
          o[r] = (bf16)(v / (1.f + __expf(-s2)));
        }
        *(bf16x4*)(outB + idx) = o;
      } else if (EPI == 2) {
        float4 b4 = *(const float4*)(bias + col0);
        float4 g4 = *(const float4*)(ada + b * ADA_STRIDE + gOff + col0);
        float4 r4 = *(const float4*)(resid + idx);
        float4 o4;
        o4.x = r4.x + g4.x * (acc[mi][ni][0] + b4.x);
        o4.y = r4.y + g4.y * (acc[mi][ni][1] + b4.y);
        o4.z = r4.z + g4.z * (acc[mi][ni][2] + b4.z);
        o4.w = r4.w + g4.w * (acc[mi][ni][3] + b4.w);
        *(float4*)(outF + idx) = o4;
      } else {
        float4 b4 = *(const float4*)(bias + col0);
        float4 g4 = *(const float4*)(ada + b * ADA_STRIDE + gOff + col0);
        float4 r4 = *(const float4*)(outF + idx);
        float4 o4;
        o4.x = r4.x + g4.x * (acc[mi][ni][0] + b4.x);
        o4.y = r4.y + g4.y * (acc[mi][ni][1] + b4.y);
        o4.z = r4.z + g4.z * (acc[mi][ni][2] + b4.z);
        o4.w = r4.w + g4.w * (acc[mi][ni][3] + b4.w);
        *(float4*)(outF + idx) = o4;
      }
    }
  }
}

// ---------------------------------------------------------------------------
// MFMA windowed attention (unchanged).
// ---------------------------------------------------------------------------
#define ATTN_LDS 65536

__global__ __launch_bounds__(256, 2) void attn_kernel(
    const bf16* __restrict__ qk, const bf16* __restrict__ vt, bf16* __restrict__ o) {
  extern __shared__ char smem[];
  bf16* qbuf = (bf16*)smem;            // 128x128 swizzled (Q -> P)
  bf16* kbuf = qbuf + 128 * 128;       // 128x128 swizzled (K -> Vt)
  const int tid = threadIdx.x;
  const int lane = tid & 63;
  const int wv = tid >> 6;
  const int lm = lane & 15;
  const int quad = lane >> 4;
  const int w = blockIdx.x >> 3;
  const int h = blockIdx.x & 7;
  const int wbase = w * 128;

#pragma unroll
  for (int it = 0; it < 8; ++it) {
    int c = it * 256 + tid;
    int r = c >> 4, gst = c & 15;
    int goff = (gst ^ (r & 15)) * 8;
    const bf16* rowp = qk + (size_t)(wbase + r) * 2048 + h * 128 + goff;
    gld16(rowp, qbuf + c * 8);
    gld16(rowp + 1024, kbuf + c * 8);
  }
  __syncthreads();

  const int wq0 = wv * 32;
  f32x4 accS[8][2];
#pragma unroll
  for (int mi = 0; mi < 8; ++mi)
#pragma unroll
    for (int ni = 0; ni < 2; ++ni) accS[mi][ni] = (f32x4){0.f, 0.f, 0.f, 0.f};

#pragma unroll
  for (int s = 0; s < 4; ++s) {
    bf16x8 bq[2], ak[8];
#pragma unroll
    for (int ni = 0; ni < 2; ++ni)
      bq[ni] = *(const bf16x8*)(qbuf + (wq0 + ni * 16 + lm) * 128 + ((s * 4 + quad) ^ lm) * 8);
#pragma unroll
    for (int mi = 0; mi < 8; ++mi)
      ak[mi] = *(const bf16x8*)(kbuf + (mi * 16 + lm) * 128 + ((s * 4 + quad) ^ lm) * 8);
#pragma unroll
    for (int mi = 0; mi < 8; ++mi)
#pragma unroll
      for (int ni = 0; ni < 2; ++ni)
        accS[mi][ni] = __builtin_amdgcn_mfma_f32_16x16x32_bf16(ak[mi], bq[ni], accS[mi][ni], 0, 0, 0);
  }

  const float scl = 0.08838834764831845f;  // 1/sqrt(128)
  float mx[2] = {-1e30f, -1e30f}, sm[2] = {0.f, 0.f};
#pragma unroll
  for (int mi = 0; mi < 8; ++mi)
#pragma unroll
    for (int ni = 0; ni < 2; ++ni)
#pragma unroll
      for (int r = 0; r < 4; ++r) {
        accS[mi][ni][r] *= scl;
        mx[ni] = fmaxf(mx[ni], accS[mi][ni][r]);
      }
#pragma unroll
  for (int ni = 0; ni < 2; ++ni) {
    mx[ni] = fmaxf(mx[ni], __shfl_xor(mx[ni], 16, 64));
    mx[ni] = fmaxf(mx[ni], __shfl_xor(mx[ni], 32, 64));
  }
#pragma unroll
  for (int mi = 0; mi < 8; ++mi)
#pragma unroll
    for (int ni = 0; ni < 2; ++ni)
#pragma unroll
      for (int r = 0; r < 4; ++r) {
        accS[mi][ni][r] = __expf(accS[mi][ni][r] - mx[ni]);
        sm[ni] += accS[mi][ni][r];
      }
#pragma unroll
  for (int ni = 0; ni < 2; ++ni) {
    sm[ni] += __shfl_xor(sm[ni], 16, 64);
    sm[ni] += __shfl_xor(sm[ni], 32, 64);
    sm[ni] = 1.f / sm[ni];
  }
  __syncthreads();

#pragma unroll
  for (int mi = 0; mi < 8; ++mi)
#pragma unroll
    for (int ni = 0; ni < 2; ++ni) {
      int q = wq0 + ni * 16 + lm;
      int gst = (mi * 2 + (quad >> 1)) ^ lm;
      bf16x4 pk;
#pragma unroll
      for (int r = 0; r < 4; ++r) pk[r] = (bf16)(accS[mi][ni][r] * sm[ni]);
      *(bf16x4*)(qbuf + q * 128 + gst * 8 + (quad & 1) * 4) = pk;
    }
#pragma unroll
  for (int it = 0; it < 8; ++it) {
    int c = it * 256 + tid;
    int r = c >> 4, gst = c & 15;
    gld16(vt + (size_t)(h * 128 + r) * 32768 + wbase + (gst ^ (r & 15)) * 8, kbuf + c * 8);
  }
  __syncthreads();

  f32x4 accO[2][8];
#pragma unroll
  for (int mi = 0; mi < 2; ++mi)
#pragma unroll
    for (int ni = 0; ni < 8; ++ni) accO[mi][ni] = (f32x4){0.f, 0.f, 0.f, 0.f};
#pragma unroll
  for (int s = 0; s < 4; ++s) {
    bf16x8 ap[2], bv[8];
#pragma unroll
    for (int mi = 0; mi < 2; ++mi)
      ap[mi] = *(const bf16x8*)(qbuf + (wq0 + mi * 16 + lm) * 128 + ((s * 4 + quad) ^ lm) * 8);
#pragma unroll
    for (int ni = 0; ni < 8; ++ni)
      bv[ni] = *(const bf16x8*)(kbuf + (ni * 16 + lm) * 128 + ((s * 4 + quad) ^ lm) * 8);
#pragma unroll
    for (int mi = 0; mi < 2; ++mi)
#pragma unroll
      for (int ni = 0; ni < 8; ++ni)
        accO[mi][ni] = __builtin_amdgcn_mfma_f32_16x16x32_bf16(ap[mi], bv[ni], accO[mi][ni], 0, 0, 0);
  }

#pragma unroll
  for (int mi = 0; mi < 2; ++mi)
#pragma unroll
    for (int ni = 0; ni < 8; ++ni) {
      int d = ni * 16 + lm;
#pragma unroll
      for (int r = 0; r < 4; ++r) {
        int q = wq0 + mi * 16 + quad * 4 + r;
        o[(size_t)(wbase + q) * 1024 + h * 128 + d] = (bf16)accO[mi][ni][r];
      }
    }
}

// ---------------------------------------------------------------------------
extern "C" void kernel_launch(void* const* d_in, const int* in_sizes, int n_in,
                              void* d_out, int out_size, void* d_ws, size_t ws_size,
                              hipStream_t stream) {
  const float* group_x = (const float*)d_in[0];
  const float* context = (const float*)d_in[1];
  const float* W_ada   = (const float*)d_in[2];
  const float* b_ada   = (const float*)d_in[3];
  const float* scale1  = (const float*)d_in[4];
  const float* W_qkv   = (const float*)d_in[5];
  const float* b_qkv   = (const float*)d_in[6];
  const float* W_out   = (const float*)d_in[7];
  const float* b_out   = (const float*)d_in[8];
  const float* scale2  = (const float*)d_in[9];
  const float* W_ff1   = (const float*)d_in[10];
  const float* b_ff1   = (const float*)d_in[11];
  const float* W_ff2   = (const float*)d_in[12];
  const float* b_ff2   = (const float*)d_in[13];
  float* out = (float*)d_out;

  char* ws = (char*)d_ws;
  float* ada   = (float*)ws;                          // 196,608 B
  bf16* wqkv_t = (bf16*)(ws + 196608);                // 3072x1024 (rows 2048.. are Wv^T)
  bf16* wout_t = wqkv_t + (size_t)3072 * 1024;        // 1024x1024
  bf16* wff1_t = wout_t + (size_t)1024 * 1024;        // 4096x1024
  bf16* wff2_t = wff1_t + (size_t)4096 * 1024;        // 1024x4096
  bf16* bufX   = wff2_t + (size_t)1024 * 4096;        // 32768x1024 (xmod -> o -> hmod)
  bf16* qkvQK  = bufX + (size_t)ROWS_TOTAL * 1024;    // 32768x2048 (roped in place)
  bf16* vtbuf  = qkvQK + (size_t)ROWS_TOTAL * 2048;   // 1024x32768
  bf16* h1     = qkvQK;                               // 32768x4096 aliases qkvQK+vtbuf

  // 0) weight convert+transpose
  wconvert_t<<<dim3(3072 * 1024 / 256), 256, 0, stream>>>(W_qkv, wqkv_t, 10, 3072, 3072 * 1024);
  wconvert_t<<<dim3(1024 * 1024 / 256), 256, 0, stream>>>(W_out, wout_t, 10, 1024, 1024 * 1024);
  wconvert_t<<<dim3(4096 * 1024 / 256), 256, 0, stream>>>(W_ff1, wff1_t, 10, 4096, 4096 * 1024);
  wconvert_t<<<dim3(1024 * 4096 / 256), 256, 0, stream>>>(W_ff2, wff2_t, 12, 1024, 1024 * 4096);

  // 1) ada
  ada_gemm<<<dim3(ADA_STRIDE / 256, 8), 256, 0, stream>>>(context, W_ada, b_ada, ada);

  // 2) xmod
  rmsnorm_mod<<<ROWS_TOTAL, 256, 0, stream>>>(group_x, scale1, ada, 0, 1024, bufX);

  // dynamic-LDS caps for the 256^2 GEMM instantiations
  hipFuncSetAttribute(reinterpret_cast<const void*>(&gemm256<0>),
                      hipFuncAttributeMaxDynamicSharedMemorySize, GEMM_LDS);
  hipFuncSetAttribute(reinterpret_cast<const void*>(&gemm256<1>),
                      hipFuncAttributeMaxDynamicSharedMemorySize, GEMM_LDS);
  hipFuncSetAttribute(reinterpret_cast<const void*>(&gemm256<2>),
                      hipFuncAttributeMaxDynamicSharedMemorySize, GEMM_LDS);
  hipFuncSetAttribute(reinterpret_cast<const void*>(&gemm256<3>),
                      hipFuncAttributeMaxDynamicSharedMemorySize, GEMM_LDS);
  hipFuncSetAttribute(reinterpret_cast<const void*>(&gemm256<4>),
                      hipFuncAttributeMaxDynamicSharedMemorySize, GEMM_LDS);

  // 3a) qk = xmod @ W_qk + b   (M=32768, N=2048, K=1024)
  gemm256<0><<<dim3(128 * 8), 512, GEMM_LDS, stream>>>(
      bufX, wqkv_t, b_qkv, ROWS_TOTAL, 1024, 2048, qkvQK, nullptr, nullptr, nullptr, 0);

  // 3b) vT[vfeat][token] = Wv^T @ xmod^T + b_v[row]  (M=1024, N=32768)
  gemm256<4><<<dim3(4 * 128), 512, GEMM_LDS, stream>>>(
      wqkv_t + (size_t)2048 * 1024, bufX, b_qkv + 2048, 1024, 1024, ROWS_TOTAL,
      vtbuf, nullptr, nullptr, nullptr, 0);

  // 3c) rope q,k in place
  rope_kernel<<<dim3(ROWS_TOTAL * 32 / 256), 256, 0, stream>>>(qkvQK);

  // 4) attention -> o (bf16, reuses bufX)
  hipFuncSetAttribute(reinterpret_cast<const void*>(&attn_kernel),
                      hipFuncAttributeMaxDynamicSharedMemorySize, ATTN_LDS);
  attn_kernel<<<dim3(256 * 8), 256, ATTN_LDS, stream>>>(qkvQK, vtbuf, bufX);

  // 5) res2 = group_x + g_msa * (o @ W_out + b_out)  -> d_out (fp32)
  gemm256<2><<<dim3(128 * 4), 512, GEMM_LDS, stream>>>(
      bufX, wout_t, b_out, ROWS_TOTAL, 1024, 1024, nullptr, out, group_x, ada, 2048);

  // 6) hmod
  rmsnorm_mod<<<ROWS_TOTAL, 256, 0, stream>>>(out, scale2, ada, 3072, 4096, bufX);

  // 7) h1 = gelu(hmod @ W_ff1 + b_ff1)  (M=32768, N=4096, K=1024)
  gemm256<1><<<dim3(128 * 16), 512, GEMM_LDS, stream>>>(
      bufX, wff1_t, b_ff1, ROWS_TOTAL, 1024, 4096, h1, nullptr, nullptr, nullptr, 0);

  // 8) d_out = res2 + g_mlp * (h1 @ W_ff2 + b_ff2)  (K=4096)
  gemm256<3><<<dim3(128 * 4), 512, GEMM_LDS, stream>>>(
      h1, wff2_t, b_ff2, ROWS_TOTAL, 4096, 1024, nullptr, out, nullptr, ada, 5120);
}